// Round 18
// baseline (221.313 us; speedup 1.0000x reference)
//
#include <hip/hip_runtime.h>

// Problem sizes: N=64, C=64, T=300, V=25, S=3, inter=16
typedef __bf16 bf16;
typedef bf16 bf16x8 __attribute__((ext_vector_type(8)));
typedef bf16 bf16x4 __attribute__((ext_vector_type(4)));
typedef float f32x4 __attribute__((ext_vector_type(4)));
typedef short s16x4 __attribute__((ext_vector_type(4)));

// ---- workspace byte offsets (total ~74.6 MB) ----
// XG holds x[n][t][v][c] bf16 until k3, which overwrites it in-place with y (same layout).
#define WS_XG    0u           // bf16 [64][300][25][64]  + 64KB pad
#define WS_WAB   61505536u    // bf16 [3][32][64]   rows 0-15=Wa, 16-31=Wb
#define WS_WD    61517824u    // bf16 [3][64][64]
#define WS_COEFA 61542400u    // f32  [64]  bn scale
#define WS_COEFB 61542656u    // f32  [64]  bn bias (incl. bd-sum)
#define WS_GT    61542912u    // bf16 [64][3][32][32]  GT[w][v]=G[v][w], zero-padded
#define WS_MPART 61936128u    // f32  [64][12][3][32][32] M partials (dead after k1b)
#define WS_STP   61936128u    // f32  [64][16][64][25]  sum-over-t(y) partials (union w/ MPART)
#define WS_SVP   68489728u    // bf16 [64][304][64]  sum_v y*(1+se1) (union w/ MPART tail)
#define WS_SE1   74519040u    // f32  [64][32]   1+se1[v]
#define WS_SE2   74527232u    // f32  [64][304]  1+se2[t]
#define WS_SE3   74605056u    // f32  [64][64]   1+se3[c]

__device__ __forceinline__ f32x4 mfma16(bf16x8 a, bf16x8 b, f32x4 c) {
  return __builtin_amdgcn_mfma_f32_16x16x32_bf16(a, b, c, 0, 0, 0);
}

// K=16 legacy MFMA: A/B frag = lane{row=l&15, k=4*(l>>4)+j} == stage1 C-layout.
#if __has_builtin(__builtin_amdgcn_mfma_f32_16x16x16_bf16)
__device__ __forceinline__ f32x4 mfma16k(bf16x4 a, bf16x4 b, f32x4 c) {
  return __builtin_amdgcn_mfma_f32_16x16x16_bf16(a, b, c, 0, 0, 0);
}
#elif __has_builtin(__builtin_amdgcn_mfma_f32_16x16x16bf16_1k)
__device__ __forceinline__ f32x4 mfma16k(bf16x4 a, bf16x4 b, f32x4 c) {
  s16x4 ai = __builtin_bit_cast(s16x4, a);
  s16x4 bi = __builtin_bit_cast(s16x4, b);
  return __builtin_amdgcn_mfma_f32_16x16x16bf16_1k(ai, bi, c, 0, 0, 0);
}
#else
__device__ __forceinline__ f32x4 mfma16k(bf16x4 a, bf16x4 b, f32x4 c) {
  asm volatile("v_mfma_f32_16x16x16_bf16 %0, %1, %2, %0" : "+v"(c) : "v"(a), "v"(b));
  return c;
}
#endif

// ---------------- k_tr v4: transpose x -> XG bf16, 4-t tiles (13 KB LDS -> 12 blk/CU) ----------------
// grid (76 tc, 64 n), 256 thr. tc<75: 4-t transpose tiles. tc==75,n==0: weight prep.
__global__ __launch_bounds__(256) void k_tr(
    const float* __restrict__ x,
    const float* __restrict__ Wa, const float* __restrict__ Wb,
    const float* __restrict__ Wd, const float* __restrict__ bd,
    const float* __restrict__ gam, const float* __restrict__ bet,
    const float* __restrict__ mean, const float* __restrict__ var,
    char* __restrict__ ws) {
  __shared__ __attribute__((aligned(16))) bf16 tile[64*102];  // [c][tv 100 pad102]
  const int tc = blockIdx.x, n = blockIdx.y, tid = threadIdx.x;
  if (tc == 75) {
    if (n != 0) return;
    bf16* wab = (bf16*)(ws + WS_WAB);
    bf16* wd  = (bf16*)(ws + WS_WD);
    float* cA = (float*)(ws + WS_COEFA);
    float* cB = (float*)(ws + WS_COEFB);
    for (int f = tid; f < 3*32*64; f += 256) {
      int s = f >> 11, r = (f >> 6) & 31, c = f & 63;
      float v = (r < 16) ? Wa[(s*16 + r)*64 + c] : Wb[(s*16 + (r-16))*64 + c];
      wab[f] = (bf16)v;
    }
    for (int f = tid; f < 3*64*64; f += 256) wd[f] = (bf16)Wd[f];
    if (tid < 64) {
      float bds = bd[tid] + bd[64+tid] + bd[128+tid];
      float iv = gam[tid] / sqrtf(var[tid] + 1e-5f);
      cA[tid] = iv;
      cB[tid] = (bds - mean[tid]) * iv + bet[tid];
    }
    return;
  }
  const int t0 = tc*4;                    // 75*4 = 300 exact, no ragged tail
  bf16* XG = (bf16*)(ws + WS_XG);
  // phase A: coalesced float4 reads of x rows (100 tv per c), bf16x4 LDS writes
  #pragma unroll
  for (int it = 0; it < 7; ++it) {
    int u = it*256 + tid;
    if (u < 1600) {
      int c = u / 25, q = u % 25;
      int idx = 4*q;
      float4 val = *(const float4*)(x + (size_t)(n*64 + c)*7500 + t0*25 + idx);
      bf16x4 pk = {(bf16)val.x, (bf16)val.y, (bf16)val.z, (bf16)val.w};
      *(bf16x4*)&tile[c*102 + idx] = pk;
    }
  }
  __syncthreads();
  // phase B: 8-way bf16 gather, 16B coalesced global stores
  #pragma unroll
  for (int it = 0; it < 4; ++it) {
    int u = it*256 + tid;
    if (u < 800) {
      int c8 = u & 7, tv = u >> 3;
      int t = t0 + tv/25, v = tv % 25;
      bf16x8 pk;
      #pragma unroll
      for (int j = 0; j < 8; ++j) pk[j] = tile[(c8*8 + j)*102 + tv];
      *(bf16x8*)&XG[((size_t)(n*300 + t)*25 + v)*64 + c8*8] = pk;
    }
  }
}

// ---------------- K1: BARRIER-FREE fused a,b projection + M accumulation ----------------
// grid (12 seg, 64 n) = 768 blocks = exactly 3/CU residency (no dispatch tail).
__global__ __launch_bounds__(256, 3) void k1_m(
    const float* __restrict__ ba_g, const float* __restrict__ bb_g,
    char* __restrict__ ws) {
  __shared__ float red[4][32][33];   // 16.9 KB
  const int seg = blockIdx.x, n = blockIdx.y;
  const int tid = threadIdx.x;
  const int lane = tid & 63, wv = tid >> 6;
  const int l15 = lane & 15, l4 = lane >> 4;
  const int t0 = seg*25, tlen = 25;
  const bf16* XG  = (const bf16*)(ws + WS_XG);
  const bf16* wab = (const bf16*)(ws + WS_WAB);
  const f32x4 z4 = {0.f,0.f,0.f,0.f};

  bf16x8 Afr[6][2];
  float bias[6][4];
  #pragma unroll
  for (int rt = 0; rt < 6; ++rt) {
    const int s = rt >> 1, abk = rt & 1;
    #pragma unroll
    for (int kk = 0; kk < 2; ++kk)
      Afr[rt][kk] = *(const bf16x8*)&wab[(s*32 + abk*16 + l15)*64 + kk*32 + 8*l4];
    const float* bp = abk ? bb_g : ba_g;
    #pragma unroll
    for (int r = 0; r < 4; ++r) bias[rt][r] = bp[s*16 + 4*l4 + r];
  }
  f32x4 macc[3][2][2] = {};
  const int tb = (tlen*wv) >> 2, te = (tlen*(wv+1)) >> 2;

  for (int tl = tb; tl < te; ++tl) {
    const size_t rowb = (size_t)(n*300 + t0 + tl)*25;
    bf16x8 Bv[2][2];
    #pragma unroll
    for (int vt = 0; vt < 2; ++vt)
      #pragma unroll
      for (int kk = 0; kk < 2; ++kk)
        Bv[vt][kk] = *(const bf16x8*)&XG[(rowb + vt*16 + l15)*64 + kk*32 + 8*l4];
    #pragma unroll
    for (int s = 0; s < 3; ++s) {
      f32x4 acc[2][2];   // [ab][vt]
      #pragma unroll
      for (int ab = 0; ab < 2; ++ab)
        #pragma unroll
        for (int vt = 0; vt < 2; ++vt) {
          f32x4 a = mfma16(Afr[2*s + ab][0], Bv[vt][0], z4);
          acc[ab][vt] = mfma16(Afr[2*s + ab][1], Bv[vt][1], a);
        }
      bf16x4 af[2], bf_[2];
      #pragma unroll
      for (int vt = 0; vt < 2; ++vt) {
        #pragma unroll
        for (int r = 0; r < 4; ++r) {
          af[vt][r]  = (bf16)(acc[0][vt][r] + bias[2*s][r]);
          bf_[vt][r] = (bf16)(acc[1][vt][r] + bias[2*s + 1][r]);
        }
      }
      #pragma unroll
      for (int vt = 0; vt < 2; ++vt)
        #pragma unroll
        for (int wt = 0; wt < 2; ++wt)
          macc[s][vt][wt] = mfma16k(af[vt], bf_[wt], macc[s][vt][wt]);
    }
  }
  float* mp = (float*)(ws + WS_MPART);
  #pragma unroll
  for (int s = 0; s < 3; ++s) {
    __syncthreads();
    #pragma unroll
    for (int vt = 0; vt < 2; ++vt)
      #pragma unroll
      for (int wt = 0; wt < 2; ++wt)
        #pragma unroll
        for (int r = 0; r < 4; ++r)
          red[wv][vt*16 + 4*l4 + r][wt*16 + l15] = macc[s][vt][wt][r];
    __syncthreads();
    for (int e = tid; e < 1024; e += 256) {
      int v = e >> 5, w = e & 31;
      float sum = red[0][v][w] + red[1][v][w] + red[2][v][w] + red[3][v][w];
      mp[(((n*12 + seg)*3 + s)*32 + v)*32 + w] = sum;
    }
  }
}

// ---------------- K1b: reduce M partials (12) -> GT (bf16, transposed, zero-padded) ----------------
__global__ __launch_bounds__(256) void k1b_g(
    const float* __restrict__ A, const float* __restrict__ alp,
    char* __restrict__ ws) {
  int e = blockIdx.x*256 + threadIdx.x;   // 196608 exact
  int w = e & 31, v = (e >> 5) & 31;
  int s = (e >> 10) % 3, n = e / 3072;
  const float* mp = (const float*)(ws + WS_MPART);
  float m = 0.f;
  #pragma unroll
  for (int p = 0; p < 12; ++p)
    m += mp[(((n*12 + p)*3 + s)*32 + v)*32 + w];
  float g = 0.f;
  if (v < 25 && w < 25)
    g = A[(s*25 + v)*25 + w] + alp[0] * tanhf(m * (1.f/4800.f));
  bf16* gt = (bf16*)(ws + WS_GT);
  gt[((n*3 + s)*32 + w)*32 + v] = (bf16)g;   // transposed write
}

// ---------------- K3 (r8 v1, best measured): BARRIER-FREE graph conv; y bf16 in-place ----------------
__global__ __launch_bounds__(256, 4) void k3_y(char* __restrict__ ws) {
  __shared__ __attribute__((aligned(16))) bf16 wdL[3*64*72];   // [s][o64][c64 pad72], 27.6 KB
  __shared__ __attribute__((aligned(16))) bf16 ULs[4*16*96];   // per-wave [o16][k96], 12.3 KB
  const int seg = blockIdx.x, n = blockIdx.y;
  const int tid = threadIdx.x, lane = tid & 63, wv = tid >> 6;
  const int l15 = lane & 15, l4 = lane >> 4;
  const int t0 = seg*19, tlen = min(19, 300 - t0);
  const bf16* XG = (const bf16*)(ws + WS_XG);
  bf16* YG = (bf16*)(ws + WS_XG);
  const bf16* wd = (const bf16*)(ws + WS_WD);
  const bf16* gt = (const bf16*)(ws + WS_GT);
  const float* cA = (const float*)(ws + WS_COEFA);
  const float* cB = (const float*)(ws + WS_COEFB);
  const f32x4 z4 = {0.f,0.f,0.f,0.f};
  bf16* UL = &ULs[wv*16*96];

  for (int f = tid; f < 1536; f += 256) {
    int row = f >> 3, c8 = f & 7;
    *(bf16x8*)&wdL[row*72 + c8*8] = *(const bf16x8*)&wd[row*64 + c8*8];
  }
  bf16x8 Gfr[2][3];
  #pragma unroll
  for (int wt = 0; wt < 2; ++wt)
    #pragma unroll
    for (int s = 0; s < 3; ++s)
      Gfr[wt][s] = *(const bf16x8*)&gt[((n*3 + s)*32 + wt*16 + l15)*32 + 8*l4];
  __syncthreads();   // the only pre-loop barrier

  const int tb = (tlen*wv) >> 2, te = (tlen*(wv+1)) >> 2;
  float st[4][2][4] = {};

  for (int tl = tb; tl < te; ++tl) {
    const size_t rowb = (size_t)(n*300 + t0 + tl)*25;
    bf16x8 Bv[2][2];
    #pragma unroll
    for (int vt = 0; vt < 2; ++vt)
      #pragma unroll
      for (int kk = 0; kk < 2; ++kk)
        Bv[vt][kk] = *(const bf16x8*)&XG[(rowb + vt*16 + l15)*64 + kk*32 + 8*l4];
    #pragma unroll
    for (int ot = 0; ot < 4; ++ot) {
      #pragma unroll
      for (int s = 0; s < 3; ++s) {
        bf16x8 W0 = *(const bf16x8*)&wdL[(s*64 + ot*16 + l15)*72 + 8*l4];
        bf16x8 W1 = *(const bf16x8*)&wdL[(s*64 + ot*16 + l15)*72 + 32 + 8*l4];
        #pragma unroll
        for (int vt = 0; vt < 2; ++vt) {
          f32x4 acc = mfma16(W0, Bv[vt][0], z4);
          acc = mfma16(W1, Bv[vt][1], acc);
          #pragma unroll
          for (int r = 0; r < 4; ++r)
            UL[(4*l4 + r)*96 + s*32 + vt*16 + l15] = (bf16)acc[r];
        }
      }
      f32x4 acc2[2] = {z4, z4};
      #pragma unroll
      for (int s = 0; s < 3; ++s) {
        bf16x8 Aa = *(const bf16x8*)&UL[l15*96 + s*32 + 8*l4];
        acc2[0] = mfma16(Aa, Gfr[0][s], acc2[0]);
        acc2[1] = mfma16(Aa, Gfr[1][s], acc2[1]);
      }
      const int o0 = ot*16 + 4*l4;
      const f32x4 cAr = *(const f32x4*)&cA[o0];
      const f32x4 cBr = *(const f32x4*)&cB[o0];
      #pragma unroll
      for (int wt = 0; wt < 2; ++wt) {
        const int w = wt*16 + l15;
        bf16x4 Rx = *(const bf16x4*)&XG[(rowb + w)*64 + o0];
        if (w < 25) {
          bf16x4 pk;
          #pragma unroll
          for (int r = 0; r < 4; ++r) {
            float val = fmaxf(acc2[wt][r]*cAr[r] + cBr[r] + (float)Rx[r], 0.f);
            pk[r] = (bf16)val;
            st[ot][wt][r] += val;
          }
          *(bf16x4*)&YG[(rowb + w)*64 + o0] = pk;
        }
      }
    }
  }
  // cross-wave reduction of per-wave t-partial sums -> stp (reuses wdL space)
  float* LDSf = (float*)wdL;                 // [4 wv][32 o][33 w]
  float* stp = (float*)(ws + WS_STP);
  #pragma unroll
  for (int half = 0; half < 2; ++half) {
    __syncthreads();
    #pragma unroll
    for (int ot2 = 0; ot2 < 2; ++ot2)
      #pragma unroll
      for (int wt = 0; wt < 2; ++wt)
        #pragma unroll
        for (int r = 0; r < 4; ++r)
          LDSf[wv*1056 + (ot2*16 + 4*l4 + r)*33 + wt*16 + l15] = st[half*2 + ot2][wt][r];
    __syncthreads();
    for (int e = tid; e < 800; e += 256) {
      int o = e / 25, w = e % 25;
      float sum = LDSf[o*33 + w] + LDSf[1056 + o*33 + w]
                + LDSf[2112 + o*33 + w] + LDSf[3168 + o*33 + w];
      stp[((n*16 + seg)*64 + half*32 + o)*25 + w] = sum;
    }
  }
}

// ---------------- K5 v2: fused se1 prologue + weighted sum over V -> svp bf16 ----------------
__global__ __launch_bounds__(256) void k5_sv(
    const float* __restrict__ Wsa, const float* __restrict__ bsa,
    char* __restrict__ ws) {
  __shared__ float Sm[64][26];
  __shared__ float red[25][8];
  __shared__ float w1[25];
  const int tq = blockIdx.x, n = blockIdx.y;
  const int tid = threadIdx.x;
  const float* stp = (const float*)(ws + WS_STP);
  const bf16* YG = (const bf16*)(ws + WS_XG);
  bf16* svp = (bf16*)(ws + WS_SVP);

  // ---- se1 prologue (redundant per block; stp is L2-hot) ----
  for (int f = tid; f < 1600; f += 256) {
    int c = f / 25, v = f % 25;
    float s = 0.f;
    #pragma unroll
    for (int p = 0; p < 16; ++p) s += stp[((n*16 + p)*64 + c)*25 + v];
    Sm[c][v] = s * (1.f/300.f);
  }
  __syncthreads();
  if (tid < 200) {
    int v = tid >> 3, part = tid & 7;
    float acc = 0.f;
    for (int c = part; c < 64; c += 8) {
      #pragma unroll
      for (int k = 0; k < 25; ++k) {
        int vv = v + k - 12;
        if (vv >= 0 && vv < 25) acc += Wsa[c*25 + k] * Sm[c][vv];
      }
    }
    red[v][part] = acc;
  }
  __syncthreads();
  if (tid < 25) {
    float a = bsa[0];
    #pragma unroll
    for (int p = 0; p < 8; ++p) a += red[tid][p];
    float f1 = 1.f + 1.f/(1.f + expf(-a));
    w1[tid] = f1;
    if (tq == 0) ((float*)(ws + WS_SE1))[n*32 + tid] = f1;
  }
  __syncthreads();
  // ---- svp main phase ----
  const int c8 = tid & 7, ts = tid >> 3;   // 32 t-slots x 8 c-blocks
  if (ts < 30) {
    const int t = tq*30 + ts;
    float acc[8] = {};
    #pragma unroll
    for (int v = 0; v < 25; ++v) {
      bf16x8 yv = *(const bf16x8*)&YG[(((size_t)n*300 + t)*25 + v)*64 + c8*8];
      #pragma unroll
      for (int j = 0; j < 8; ++j) acc[j] += w1[v] * (float)yv[j];
    }
    bf16x8 pk;
    #pragma unroll
    for (int j = 0; j < 8; ++j) pk[j] = (bf16)acc[j];
    *(bf16x8*)&svp[((size_t)n*304 + t)*64 + c8*8] = pk;
  }
}

// ---------------- k_att2: se2 (temporal conv) + se3 (squeeze-excite) from svp ----------------
__global__ __launch_bounds__(1024) void k_att2(
    const float* __restrict__ Wta, const float* __restrict__ bta,
    const float* __restrict__ Wfc1, const float* __restrict__ bfc1,
    const float* __restrict__ Wfc2, const float* __restrict__ bfc2,
    char* __restrict__ ws) {
  __shared__ bf16 Sv[64][304];
  __shared__ float WLa[576];
  __shared__ float redt[304][4];
  __shared__ float w2s[304];
  __shared__ float red2[64][16];
  __shared__ float mS[64];
  __shared__ float hS[32];
  const int n = blockIdx.x, tid = threadIdx.x;
  const bf16* svp = (const bf16*)(ws + WS_SVP);

  for (int u = tid; u < 300*64; u += 1024) {
    int t = u >> 6, c = u & 63;
    Sv[c][t] = svp[((size_t)n*304 + t)*64 + c];
  }
  for (int f = tid; f < 576; f += 1024) WLa[f] = Wta[f];
  __syncthreads();
  for (int u = tid; u < 1200; u += 1024) {
    int t = u >> 2, part = u & 3;
    float acc = 0.f;
    for (int c = part*16; c < part*16 + 16; ++c) {
      #pragma unroll
      for (int k = 0; k < 9; ++k) {
        int t2 = t + k - 4;
        if (t2 >= 0 && t2 < 300) acc += WLa[c*9 + k] * (float)Sv[c][t2];
      }
    }
    redt[t][part] = acc;
  }
  __syncthreads();
  if (tid < 300) {
    float a = (redt[tid][0] + redt[tid][1] + redt[tid][2] + redt[tid][3]) * (1.f/25.f) + bta[0];
    float f2 = 1.f + 1.f/(1.f + expf(-a));
    w2s[tid] = f2;
    ((float*)(ws + WS_SE2))[n*304 + tid] = f2;
  }
  __syncthreads();
  {
    int c = tid & 63, part = tid >> 6;
    int tb = part*19, te = min(tb + 19, 300);
    float acc = 0.f;
    for (int t = tb; t < te; ++t) acc += w2s[t] * (float)Sv[c][t];
    red2[c][part] = acc;
  }
  __syncthreads();
  if (tid < 64) {
    float mm = 0.f;
    #pragma unroll
    for (int p = 0; p < 16; ++p) mm += red2[tid][p];
    mS[tid] = mm * (1.f/7500.f);
  }
  __syncthreads();
  if (tid < 32) {
    float a = bfc1[tid];
    for (int c = 0; c < 64; ++c) a += Wfc1[tid*64 + c] * mS[c];
    hS[tid] = fmaxf(a, 0.f);
  }
  __syncthreads();
  if (tid < 64) {
    float a = bfc2[tid];
    #pragma unroll
    for (int j = 0; j < 32; ++j) a += Wfc2[tid*32 + j] * hS[j];
    ((float*)(ws + WS_SE3))[n*64 + tid] = 1.f + 1.f/(1.f + expf(-a));
  }
}

// ---------------- K7 v4: scale + transpose, 2-t tiles (13 KB LDS -> 12 blk/CU) ----------------
// grid (150 tc, 64 n), 256 thr, float2 stores.
__global__ __launch_bounds__(256) void k7_scale(
    const char* __restrict__ ws, float* __restrict__ out) {
  __shared__ float tile[50*65];
  __shared__ float w3S[64];
  const int tc = blockIdx.x, n = blockIdx.y, tid = threadIdx.x;
  const bf16* YG = (const bf16*)(ws + WS_XG);
  const float* w1 = (const float*)(ws + WS_SE1) + n*32;
  const float* w2 = (const float*)(ws + WS_SE2) + n*304;
  if (tid < 64) w3S[tid] = ((const float*)(ws + WS_SE3))[n*64 + tid];
  const int tb = tc*2;                    // 150*2 = 300 exact
  __syncthreads();
  // phase A: load + scale + transpose into LDS (400 units of 8 c-elems)
  #pragma unroll
  for (int it = 0; it < 2; ++it) {
    int u = it*256 + tid;
    if (u < 400) {
      int c8 = u & 7, rest = u >> 3;
      int v = rest % 25, dt = rest / 25;
      int t = tb + dt;
      bf16x8 val = *(const bf16x8*)&YG[(((size_t)n*300 + t)*25 + v)*64 + c8*8];
      float sc = w1[v] * w2[t];
      #pragma unroll
      for (int j = 0; j < 8; ++j)
        tile[(dt*25 + v)*65 + c8*8 + j] = (float)val[j] * sc * w3S[c8*8 + j];
    }
  }
  __syncthreads();
  // phase B: coalesced per-c rows, float2 stores (64 c x 25 q2-pairs)
  #pragma unroll
  for (int it = 0; it < 7; ++it) {
    int u = it*256 + tid;
    if (u < 1600) {
      int c = u / 25, q2 = u % 25;
      float2 o;
      o.x = tile[(2*q2)*65 + c];
      o.y = tile[(2*q2 + 1)*65 + c];
      *(float2*)&out[(size_t)(n*64 + c)*7500 + tb*25 + 2*q2] = o;
    }
  }
}

extern "C" void kernel_launch(void* const* d_in, const int* in_sizes, int n_in,
                              void* d_out, int out_size, void* d_ws, size_t ws_size,
                              hipStream_t stream) {
  const float* x    = (const float*)d_in[0];
  const float* A    = (const float*)d_in[1];
  const float* alp  = (const float*)d_in[2];
  const float* Wa   = (const float*)d_in[3];
  const float* ba   = (const float*)d_in[4];
  const float* Wb   = (const float*)d_in[5];
  const float* bb   = (const float*)d_in[6];
  const float* Wd   = (const float*)d_in[7];
  const float* bd   = (const float*)d_in[8];
  const float* gam  = (const float*)d_in[9];
  const float* bet  = (const float*)d_in[10];
  const float* mean = (const float*)d_in[11];
  const float* var  = (const float*)d_in[12];
  const float* Wsa  = (const float*)d_in[13];
  const float* bsa  = (const float*)d_in[14];
  const float* Wta  = (const float*)d_in[15];
  const float* bta  = (const float*)d_in[16];
  const float* Wfc1 = (const float*)d_in[17];
  const float* bfc1 = (const float*)d_in[18];
  const float* Wfc2 = (const float*)d_in[19];
  const float* bfc2 = (const float*)d_in[20];
  char* ws = (char*)d_ws;
  float* out = (float*)d_out;

  k_tr<<<dim3(76, 64), dim3(256), 0, stream>>>(x, Wa, Wb, Wd, bd, gam, bet, mean, var, ws);
  k1_m<<<dim3(12, 64), dim3(256), 0, stream>>>(ba, bb, ws);
  k1b_g<<<dim3(768), dim3(256), 0, stream>>>(A, alp, ws);
  k3_y<<<dim3(16, 64), dim3(256), 0, stream>>>(ws);
  k5_sv<<<dim3(10, 64), dim3(256), 0, stream>>>(Wsa, bsa, ws);
  k_att2<<<dim3(64), dim3(1024), 0, stream>>>(Wta, bta, Wfc1, bfc1, Wfc2, bfc2, ws);
  k7_scale<<<dim3(150, 64), dim3(256), 0, stream>>>(ws, out);
}

// Round 19
// 214.941 us; speedup vs baseline: 1.0296x; 1.0296x over previous
//
#include <hip/hip_runtime.h>

// Problem sizes: N=64, C=64, T=300, V=25, S=3, inter=16
typedef __bf16 bf16;
typedef bf16 bf16x8 __attribute__((ext_vector_type(8)));
typedef bf16 bf16x4 __attribute__((ext_vector_type(4)));
typedef float f32x4 __attribute__((ext_vector_type(4)));
typedef short s16x4 __attribute__((ext_vector_type(4)));

// ---- workspace byte offsets (total ~74.6 MB) ----
// XG holds x[n][t][v][c] bf16 until k3, which overwrites it in-place with y (same layout).
#define WS_XG    0u           // bf16 [64][300][25][64]  + 64KB pad
#define WS_WAB   61505536u    // bf16 [3][32][64]   rows 0-15=Wa, 16-31=Wb
#define WS_WD    61517824u    // bf16 [3][64][64]
#define WS_COEFA 61542400u    // f32  [64]  bn scale
#define WS_COEFB 61542656u    // f32  [64]  bn bias (incl. bd-sum)
#define WS_GT    61542912u    // bf16 [64][3][32][32]  GT[w][v]=G[v][w], zero-padded
#define WS_MPART 61936128u    // f32  [64][12][3][32][32] M partials (dead after k1b)
#define WS_STP   61936128u    // f32  [64][16][64][25]  sum-over-t(y) partials (union w/ MPART)
#define WS_SVP   68489728u    // bf16 [64][304][64]  sum_v y*(1+se1) (union w/ MPART tail)
#define WS_SE1   74519040u    // f32  [64][32]   1+se1[v]
#define WS_SE2   74527232u    // f32  [64][304]  1+se2[t]
#define WS_SE3   74605056u    // f32  [64][64]   1+se3[c]

__device__ __forceinline__ f32x4 mfma16(bf16x8 a, bf16x8 b, f32x4 c) {
  return __builtin_amdgcn_mfma_f32_16x16x32_bf16(a, b, c, 0, 0, 0);
}

// K=16 legacy MFMA: A/B frag = lane{row=l&15, k=4*(l>>4)+j} == stage1 C-layout.
#if __has_builtin(__builtin_amdgcn_mfma_f32_16x16x16_bf16)
__device__ __forceinline__ f32x4 mfma16k(bf16x4 a, bf16x4 b, f32x4 c) {
  return __builtin_amdgcn_mfma_f32_16x16x16_bf16(a, b, c, 0, 0, 0);
}
#elif __has_builtin(__builtin_amdgcn_mfma_f32_16x16x16bf16_1k)
__device__ __forceinline__ f32x4 mfma16k(bf16x4 a, bf16x4 b, f32x4 c) {
  s16x4 ai = __builtin_bit_cast(s16x4, a);
  s16x4 bi = __builtin_bit_cast(s16x4, b);
  return __builtin_amdgcn_mfma_f32_16x16x16bf16_1k(ai, bi, c, 0, 0, 0);
}
#else
__device__ __forceinline__ f32x4 mfma16k(bf16x4 a, bf16x4 b, f32x4 c) {
  asm volatile("v_mfma_f32_16x16x16_bf16 %0, %1, %2, %0" : "+v"(c) : "v"(a), "v"(b));
  return c;
}
#endif

// ---------------- k_tr v3: transpose x -> XG bf16; block col tc==38 does weight prep ----------------
__global__ __launch_bounds__(256) void k_tr(
    const float* __restrict__ x,
    const float* __restrict__ Wa, const float* __restrict__ Wb,
    const float* __restrict__ Wd, const float* __restrict__ bd,
    const float* __restrict__ gam, const float* __restrict__ bet,
    const float* __restrict__ mean, const float* __restrict__ var,
    char* __restrict__ ws) {
  __shared__ __attribute__((aligned(16))) bf16 tile[64*204];  // [c][tv 200 pad204]
  const int tc = blockIdx.x, n = blockIdx.y, tid = threadIdx.x;
  if (tc == 38) {
    if (n != 0) return;
    bf16* wab = (bf16*)(ws + WS_WAB);
    bf16* wd  = (bf16*)(ws + WS_WD);
    float* cA = (float*)(ws + WS_COEFA);
    float* cB = (float*)(ws + WS_COEFB);
    for (int f = tid; f < 3*32*64; f += 256) {
      int s = f >> 11, r = (f >> 6) & 31, c = f & 63;
      float v = (r < 16) ? Wa[(s*16 + r)*64 + c] : Wb[(s*16 + (r-16))*64 + c];
      wab[f] = (bf16)v;
    }
    for (int f = tid; f < 3*64*64; f += 256) wd[f] = (bf16)Wd[f];
    if (tid < 64) {
      float bds = bd[tid] + bd[64+tid] + bd[128+tid];
      float iv = gam[tid] / sqrtf(var[tid] + 1e-5f);
      cA[tid] = iv;
      cB[tid] = (bds - mean[tid]) * iv + bet[tid];
    }
    return;
  }
  const int t0 = tc*8;
  const int vmax = min(200, 7500 - t0*25);   // 200, or 100 for tc=37
  bf16* XG = (bf16*)(ws + WS_XG);
  #pragma unroll
  for (int it = 0; it < 13; ++it) {
    int u = it*256 + tid;
    if (u < 3200) {
      int c = u / 50, q = u % 50;
      int idx = 4*q;
      if (idx < vmax) {
        float4 val = *(const float4*)(x + (size_t)(n*64 + c)*7500 + t0*25 + idx);
        bf16x4 pk = {(bf16)val.x, (bf16)val.y, (bf16)val.z, (bf16)val.w};
        *(bf16x4*)&tile[c*204 + idx] = pk;
      }
    }
  }
  __syncthreads();
  #pragma unroll
  for (int it = 0; it < 7; ++it) {
    int u = it*256 + tid;
    if (u < 1600) {
      int c8 = u & 7, tv = u >> 3;
      int t = t0 + tv/25, v = tv % 25;
      if (t < 300) {
        bf16x8 pk;
        #pragma unroll
        for (int j = 0; j < 8; ++j) pk[j] = tile[(c8*8 + j)*204 + tv];
        *(bf16x8*)&XG[((size_t)(n*300 + t)*25 + v)*64 + c8*8] = pk;
      }
    }
  }
}

// ---------------- K1: BARRIER-FREE fused a,b projection + M accumulation ----------------
// grid (12 seg, 64 n) = 768 blocks = exactly 3/CU residency (no dispatch tail).
__global__ __launch_bounds__(256, 3) void k1_m(
    const float* __restrict__ ba_g, const float* __restrict__ bb_g,
    char* __restrict__ ws) {
  __shared__ float red[4][32][33];   // 16.9 KB
  const int seg = blockIdx.x, n = blockIdx.y;
  const int tid = threadIdx.x;
  const int lane = tid & 63, wv = tid >> 6;
  const int l15 = lane & 15, l4 = lane >> 4;
  const int t0 = seg*25, tlen = 25;
  const bf16* XG  = (const bf16*)(ws + WS_XG);
  const bf16* wab = (const bf16*)(ws + WS_WAB);
  const f32x4 z4 = {0.f,0.f,0.f,0.f};

  bf16x8 Afr[6][2];
  float bias[6][4];
  #pragma unroll
  for (int rt = 0; rt < 6; ++rt) {
    const int s = rt >> 1, abk = rt & 1;
    #pragma unroll
    for (int kk = 0; kk < 2; ++kk)
      Afr[rt][kk] = *(const bf16x8*)&wab[(s*32 + abk*16 + l15)*64 + kk*32 + 8*l4];
    const float* bp = abk ? bb_g : ba_g;
    #pragma unroll
    for (int r = 0; r < 4; ++r) bias[rt][r] = bp[s*16 + 4*l4 + r];
  }
  f32x4 macc[3][2][2] = {};
  const int tb = (tlen*wv) >> 2, te = (tlen*(wv+1)) >> 2;

  for (int tl = tb; tl < te; ++tl) {
    const size_t rowb = (size_t)(n*300 + t0 + tl)*25;
    bf16x8 Bv[2][2];
    #pragma unroll
    for (int vt = 0; vt < 2; ++vt)
      #pragma unroll
      for (int kk = 0; kk < 2; ++kk)
        Bv[vt][kk] = *(const bf16x8*)&XG[(rowb + vt*16 + l15)*64 + kk*32 + 8*l4];
    #pragma unroll
    for (int s = 0; s < 3; ++s) {
      f32x4 acc[2][2];   // [ab][vt]
      #pragma unroll
      for (int ab = 0; ab < 2; ++ab)
        #pragma unroll
        for (int vt = 0; vt < 2; ++vt) {
          f32x4 a = mfma16(Afr[2*s + ab][0], Bv[vt][0], z4);
          acc[ab][vt] = mfma16(Afr[2*s + ab][1], Bv[vt][1], a);
        }
      bf16x4 af[2], bf_[2];
      #pragma unroll
      for (int vt = 0; vt < 2; ++vt) {
        #pragma unroll
        for (int r = 0; r < 4; ++r) {
          af[vt][r]  = (bf16)(acc[0][vt][r] + bias[2*s][r]);
          bf_[vt][r] = (bf16)(acc[1][vt][r] + bias[2*s + 1][r]);
        }
      }
      #pragma unroll
      for (int vt = 0; vt < 2; ++vt)
        #pragma unroll
        for (int wt = 0; wt < 2; ++wt)
          macc[s][vt][wt] = mfma16k(af[vt], bf_[wt], macc[s][vt][wt]);
    }
  }
  float* mp = (float*)(ws + WS_MPART);
  #pragma unroll
  for (int s = 0; s < 3; ++s) {
    __syncthreads();
    #pragma unroll
    for (int vt = 0; vt < 2; ++vt)
      #pragma unroll
      for (int wt = 0; wt < 2; ++wt)
        #pragma unroll
        for (int r = 0; r < 4; ++r)
          red[wv][vt*16 + 4*l4 + r][wt*16 + l15] = macc[s][vt][wt][r];
    __syncthreads();
    for (int e = tid; e < 1024; e += 256) {
      int v = e >> 5, w = e & 31;
      float sum = red[0][v][w] + red[1][v][w] + red[2][v][w] + red[3][v][w];
      mp[(((n*12 + seg)*3 + s)*32 + v)*32 + w] = sum;
    }
  }
}

// ---------------- K1b: reduce M partials (12) -> GT (bf16, transposed, zero-padded) ----------------
__global__ __launch_bounds__(256) void k1b_g(
    const float* __restrict__ A, const float* __restrict__ alp,
    char* __restrict__ ws) {
  int e = blockIdx.x*256 + threadIdx.x;   // 196608 exact
  int w = e & 31, v = (e >> 5) & 31;
  int s = (e >> 10) % 3, n = e / 3072;
  const float* mp = (const float*)(ws + WS_MPART);
  float m = 0.f;
  #pragma unroll
  for (int p = 0; p < 12; ++p)
    m += mp[(((n*12 + p)*3 + s)*32 + v)*32 + w];
  float g = 0.f;
  if (v < 25 && w < 25)
    g = A[(s*25 + v)*25 + w] + alp[0] * tanhf(m * (1.f/4800.f));
  bf16* gt = (bf16*)(ws + WS_GT);
  gt[((n*3 + s)*32 + w)*32 + v] = (bf16)g;   // transposed write
}

// ---------------- K3 (r8 v1, best measured): BARRIER-FREE graph conv; y bf16 in-place ----------------
__global__ __launch_bounds__(256, 4) void k3_y(char* __restrict__ ws) {
  __shared__ __attribute__((aligned(16))) bf16 wdL[3*64*72];   // [s][o64][c64 pad72], 27.6 KB
  __shared__ __attribute__((aligned(16))) bf16 ULs[4*16*96];   // per-wave [o16][k96], 12.3 KB
  const int seg = blockIdx.x, n = blockIdx.y;
  const int tid = threadIdx.x, lane = tid & 63, wv = tid >> 6;
  const int l15 = lane & 15, l4 = lane >> 4;
  const int t0 = seg*19, tlen = min(19, 300 - t0);
  const bf16* XG = (const bf16*)(ws + WS_XG);
  bf16* YG = (bf16*)(ws + WS_XG);
  const bf16* wd = (const bf16*)(ws + WS_WD);
  const bf16* gt = (const bf16*)(ws + WS_GT);
  const float* cA = (const float*)(ws + WS_COEFA);
  const float* cB = (const float*)(ws + WS_COEFB);
  const f32x4 z4 = {0.f,0.f,0.f,0.f};
  bf16* UL = &ULs[wv*16*96];

  for (int f = tid; f < 1536; f += 256) {
    int row = f >> 3, c8 = f & 7;
    *(bf16x8*)&wdL[row*72 + c8*8] = *(const bf16x8*)&wd[row*64 + c8*8];
  }
  bf16x8 Gfr[2][3];
  #pragma unroll
  for (int wt = 0; wt < 2; ++wt)
    #pragma unroll
    for (int s = 0; s < 3; ++s)
      Gfr[wt][s] = *(const bf16x8*)&gt[((n*3 + s)*32 + wt*16 + l15)*32 + 8*l4];
  __syncthreads();   // the only pre-loop barrier

  const int tb = (tlen*wv) >> 2, te = (tlen*(wv+1)) >> 2;
  float st[4][2][4] = {};

  for (int tl = tb; tl < te; ++tl) {
    const size_t rowb = (size_t)(n*300 + t0 + tl)*25;
    bf16x8 Bv[2][2];
    #pragma unroll
    for (int vt = 0; vt < 2; ++vt)
      #pragma unroll
      for (int kk = 0; kk < 2; ++kk)
        Bv[vt][kk] = *(const bf16x8*)&XG[(rowb + vt*16 + l15)*64 + kk*32 + 8*l4];
    #pragma unroll
    for (int ot = 0; ot < 4; ++ot) {
      #pragma unroll
      for (int s = 0; s < 3; ++s) {
        bf16x8 W0 = *(const bf16x8*)&wdL[(s*64 + ot*16 + l15)*72 + 8*l4];
        bf16x8 W1 = *(const bf16x8*)&wdL[(s*64 + ot*16 + l15)*72 + 32 + 8*l4];
        #pragma unroll
        for (int vt = 0; vt < 2; ++vt) {
          f32x4 acc = mfma16(W0, Bv[vt][0], z4);
          acc = mfma16(W1, Bv[vt][1], acc);
          #pragma unroll
          for (int r = 0; r < 4; ++r)
            UL[(4*l4 + r)*96 + s*32 + vt*16 + l15] = (bf16)acc[r];
        }
      }
      f32x4 acc2[2] = {z4, z4};
      #pragma unroll
      for (int s = 0; s < 3; ++s) {
        bf16x8 Aa = *(const bf16x8*)&UL[l15*96 + s*32 + 8*l4];
        acc2[0] = mfma16(Aa, Gfr[0][s], acc2[0]);
        acc2[1] = mfma16(Aa, Gfr[1][s], acc2[1]);
      }
      const int o0 = ot*16 + 4*l4;
      const f32x4 cAr = *(const f32x4*)&cA[o0];
      const f32x4 cBr = *(const f32x4*)&cB[o0];
      #pragma unroll
      for (int wt = 0; wt < 2; ++wt) {
        const int w = wt*16 + l15;
        bf16x4 Rx = *(const bf16x4*)&XG[(rowb + w)*64 + o0];
        if (w < 25) {
          bf16x4 pk;
          #pragma unroll
          for (int r = 0; r < 4; ++r) {
            float val = fmaxf(acc2[wt][r]*cAr[r] + cBr[r] + (float)Rx[r], 0.f);
            pk[r] = (bf16)val;
            st[ot][wt][r] += val;
          }
          *(bf16x4*)&YG[(rowb + w)*64 + o0] = pk;
        }
      }
    }
  }
  // cross-wave reduction of per-wave t-partial sums -> stp (reuses wdL space)
  float* LDSf = (float*)wdL;                 // [4 wv][32 o][33 w]
  float* stp = (float*)(ws + WS_STP);
  #pragma unroll
  for (int half = 0; half < 2; ++half) {
    __syncthreads();
    #pragma unroll
    for (int ot2 = 0; ot2 < 2; ++ot2)
      #pragma unroll
      for (int wt = 0; wt < 2; ++wt)
        #pragma unroll
        for (int r = 0; r < 4; ++r)
          LDSf[wv*1056 + (ot2*16 + 4*l4 + r)*33 + wt*16 + l15] = st[half*2 + ot2][wt][r];
    __syncthreads();
    for (int e = tid; e < 800; e += 256) {
      int o = e / 25, w = e % 25;
      float sum = LDSf[o*33 + w] + LDSf[1056 + o*33 + w]
                + LDSf[2112 + o*33 + w] + LDSf[3168 + o*33 + w];
      stp[((n*16 + seg)*64 + half*32 + o)*25 + w] = sum;
    }
  }
}

// ---------------- K5 v2: fused se1 prologue + weighted sum over V -> svp bf16 ----------------
__global__ __launch_bounds__(256) void k5_sv(
    const float* __restrict__ Wsa, const float* __restrict__ bsa,
    char* __restrict__ ws) {
  __shared__ float Sm[64][26];
  __shared__ float red[25][8];
  __shared__ float w1[25];
  const int tq = blockIdx.x, n = blockIdx.y;
  const int tid = threadIdx.x;
  const float* stp = (const float*)(ws + WS_STP);
  const bf16* YG = (const bf16*)(ws + WS_XG);
  bf16* svp = (bf16*)(ws + WS_SVP);

  // ---- se1 prologue (redundant per block; stp is L2-hot) ----
  for (int f = tid; f < 1600; f += 256) {
    int c = f / 25, v = f % 25;
    float s = 0.f;
    #pragma unroll
    for (int p = 0; p < 16; ++p) s += stp[((n*16 + p)*64 + c)*25 + v];
    Sm[c][v] = s * (1.f/300.f);
  }
  __syncthreads();
  if (tid < 200) {
    int v = tid >> 3, part = tid & 7;
    float acc = 0.f;
    for (int c = part; c < 64; c += 8) {
      #pragma unroll
      for (int k = 0; k < 25; ++k) {
        int vv = v + k - 12;
        if (vv >= 0 && vv < 25) acc += Wsa[c*25 + k] * Sm[c][vv];
      }
    }
    red[v][part] = acc;
  }
  __syncthreads();
  if (tid < 25) {
    float a = bsa[0];
    #pragma unroll
    for (int p = 0; p < 8; ++p) a += red[tid][p];
    float f1 = 1.f + 1.f/(1.f + expf(-a));
    w1[tid] = f1;
    if (tq == 0) ((float*)(ws + WS_SE1))[n*32 + tid] = f1;
  }
  __syncthreads();
  // ---- svp main phase ----
  const int c8 = tid & 7, ts = tid >> 3;   // 32 t-slots x 8 c-blocks
  if (ts < 30) {
    const int t = tq*30 + ts;
    float acc[8] = {};
    #pragma unroll
    for (int v = 0; v < 25; ++v) {
      bf16x8 yv = *(const bf16x8*)&YG[(((size_t)n*300 + t)*25 + v)*64 + c8*8];
      #pragma unroll
      for (int j = 0; j < 8; ++j) acc[j] += w1[v] * (float)yv[j];
    }
    bf16x8 pk;
    #pragma unroll
    for (int j = 0; j < 8; ++j) pk[j] = (bf16)acc[j];
    *(bf16x8*)&svp[((size_t)n*304 + t)*64 + c8*8] = pk;
  }
}

// ---------------- k_att2: se2 (temporal conv) + se3 (squeeze-excite) from svp ----------------
__global__ __launch_bounds__(1024) void k_att2(
    const float* __restrict__ Wta, const float* __restrict__ bta,
    const float* __restrict__ Wfc1, const float* __restrict__ bfc1,
    const float* __restrict__ Wfc2, const float* __restrict__ bfc2,
    char* __restrict__ ws) {
  __shared__ bf16 Sv[64][304];
  __shared__ float WLa[576];
  __shared__ float redt[304][4];
  __shared__ float w2s[304];
  __shared__ float red2[64][16];
  __shared__ float mS[64];
  __shared__ float hS[32];
  const int n = blockIdx.x, tid = threadIdx.x;
  const bf16* svp = (const bf16*)(ws + WS_SVP);

  for (int u = tid; u < 300*64; u += 1024) {
    int t = u >> 6, c = u & 63;
    Sv[c][t] = svp[((size_t)n*304 + t)*64 + c];
  }
  for (int f = tid; f < 576; f += 1024) WLa[f] = Wta[f];
  __syncthreads();
  for (int u = tid; u < 1200; u += 1024) {
    int t = u >> 2, part = u & 3;
    float acc = 0.f;
    for (int c = part*16; c < part*16 + 16; ++c) {
      #pragma unroll
      for (int k = 0; k < 9; ++k) {
        int t2 = t + k - 4;
        if (t2 >= 0 && t2 < 300) acc += WLa[c*9 + k] * (float)Sv[c][t2];
      }
    }
    redt[t][part] = acc;
  }
  __syncthreads();
  if (tid < 300) {
    float a = (redt[tid][0] + redt[tid][1] + redt[tid][2] + redt[tid][3]) * (1.f/25.f) + bta[0];
    float f2 = 1.f + 1.f/(1.f + expf(-a));
    w2s[tid] = f2;
    ((float*)(ws + WS_SE2))[n*304 + tid] = f2;
  }
  __syncthreads();
  {
    int c = tid & 63, part = tid >> 6;
    int tb = part*19, te = min(tb + 19, 300);
    float acc = 0.f;
    for (int t = tb; t < te; ++t) acc += w2s[t] * (float)Sv[c][t];
    red2[c][part] = acc;
  }
  __syncthreads();
  if (tid < 64) {
    float mm = 0.f;
    #pragma unroll
    for (int p = 0; p < 16; ++p) mm += red2[tid][p];
    mS[tid] = mm * (1.f/7500.f);
  }
  __syncthreads();
  if (tid < 32) {
    float a = bfc1[tid];
    for (int c = 0; c < 64; ++c) a += Wfc1[tid*64 + c] * mS[c];
    hS[tid] = fmaxf(a, 0.f);
  }
  __syncthreads();
  if (tid < 64) {
    float a = bfc2[tid];
    #pragma unroll
    for (int j = 0; j < 32; ++j) a += Wfc2[tid*32 + j] * hS[j];
    ((float*)(ws + WS_SE3))[n*64 + tid] = 1.f + 1.f/(1.f + expf(-a));
  }
}

// ---------------- K7 v3: scale + transpose y bf16 [n][t][v][c] -> out f32 [n][c][t][v] ----------------
__global__ __launch_bounds__(256) void k7_scale(
    const char* __restrict__ ws, float* __restrict__ out) {
  __shared__ float tile[100*65];
  __shared__ float w3S[64];
  const int tc = blockIdx.x, n = blockIdx.y, tid = threadIdx.x;
  const bf16* YG = (const bf16*)(ws + WS_XG);
  const float* w1 = (const float*)(ws + WS_SE1) + n*32;
  const float* w2 = (const float*)(ws + WS_SE2) + n*304;
  if (tid < 64) w3S[tid] = ((const float*)(ws + WS_SE3))[n*64 + tid];
  const int tb = tc*4;
  __syncthreads();
  #pragma unroll
  for (int it = 0; it < 4; ++it) {
    int u = it*256 + tid;
    if (u < 800) {
      int c8 = u & 7, rest = u >> 3;
      int v = rest % 25, dt = rest / 25;
      int t = tb + dt;
      bf16x8 val = *(const bf16x8*)&YG[(((size_t)n*300 + t)*25 + v)*64 + c8*8];
      float sc = w1[v] * w2[t];
      #pragma unroll
      for (int j = 0; j < 8; ++j)
        tile[(dt*25 + v)*65 + c8*8 + j] = (float)val[j] * sc * w3S[c8*8 + j];
    }
  }
  __syncthreads();
  #pragma unroll
  for (int it = 0; it < 13; ++it) {
    int u = it*256 + tid;
    if (u < 3200) {
      int c = u / 50, q2 = u % 50;
      float2 o;
      o.x = tile[(2*q2)*65 + c];
      o.y = tile[(2*q2 + 1)*65 + c];
      *(float2*)&out[(size_t)(n*64 + c)*7500 + tb*25 + 2*q2] = o;
    }
  }
}

extern "C" void kernel_launch(void* const* d_in, const int* in_sizes, int n_in,
                              void* d_out, int out_size, void* d_ws, size_t ws_size,
                              hipStream_t stream) {
  const float* x    = (const float*)d_in[0];
  const float* A    = (const float*)d_in[1];
  const float* alp  = (const float*)d_in[2];
  const float* Wa   = (const float*)d_in[3];
  const float* ba   = (const float*)d_in[4];
  const float* Wb   = (const float*)d_in[5];
  const float* bb   = (const float*)d_in[6];
  const float* Wd   = (const float*)d_in[7];
  const float* bd   = (const float*)d_in[8];
  const float* gam  = (const float*)d_in[9];
  const float* bet  = (const float*)d_in[10];
  const float* mean = (const float*)d_in[11];
  const float* var  = (const float*)d_in[12];
  const float* Wsa  = (const float*)d_in[13];
  const float* bsa  = (const float*)d_in[14];
  const float* Wta  = (const float*)d_in[15];
  const float* bta  = (const float*)d_in[16];
  const float* Wfc1 = (const float*)d_in[17];
  const float* bfc1 = (const float*)d_in[18];
  const float* Wfc2 = (const float*)d_in[19];
  const float* bfc2 = (const float*)d_in[20];
  char* ws = (char*)d_ws;
  float* out = (float*)d_out;

  k_tr<<<dim3(39, 64), dim3(256), 0, stream>>>(x, Wa, Wb, Wd, bd, gam, bet, mean, var, ws);
  k1_m<<<dim3(12, 64), dim3(256), 0, stream>>>(ba, bb, ws);
  k1b_g<<<dim3(768), dim3(256), 0, stream>>>(A, alp, ws);
  k3_y<<<dim3(16, 64), dim3(256), 0, stream>>>(ws);
  k5_sv<<<dim3(10, 64), dim3(256), 0, stream>>>(Wsa, bsa, ws);
  k_att2<<<dim3(64), dim3(1024), 0, stream>>>(Wta, bta, Wfc1, bfc1, Wfc2, bfc2, ws);
  k7_scale<<<dim3(75, 64), dim3(256), 0, stream>>>(ws, out);
}